// Round 7
// baseline (342.555 us; speedup 1.0000x reference)
//
#include <hip/hip_runtime.h>
#include <hip/hip_bf16.h>

// GateAttentionUnit. B=16, N=512, D=1024, E=2048, S=128, F=2E+S=4224.
// CONFIRMED: all 10 inputs fp32, output fp32. Internal compute bf16 MFMA.
//
// Pipeline:
//   P  prologue (fused): rope tables | uv_w->bf16 | o_w->bf16 | layernorm
//   K2 gemm<4,EpiUV>: silu(xn @ uv_wb^T + uv_b) -> u | vT | base   [8192 x 4224]
//   K3 rope_qk:    q,k = rope(base*gamma+beta) (d_out scratch)     [8192 x 128]
//   K4 gemm<4,EpiQK>:   km = relu(q@k^T/512 + relpos)^2 (d_out)    [16][512][512]
//   K5 gemm<8,EpiAttn>: out2 = u * (km @ vT^T), out2 aliases u     [8192 x 2048]
//   K6 gemm<4,EpiOut>:  out = out2 @ o_wb^T + o_b + x  (fp32 out)  [8192 x 1024]
//
// R13 -> R14: GEMM inner loop FROZEN (R13-verified: BK=32 dbuf, stage-after-
// barrier, 663 TF = matches the documented 2-phase-structure reference rate;
// 3 sync-structure rewrites all failed to beat it). New: (a) the 4
// independent prologue kernels fused into ONE launch (block-range dispatch)
// -- removes 3 dispatch gaps; (b) GEMM block mapping swapped (x->tileN,
// y->tileM): consecutive blocks share the A panel and stream B panels ->
// K2 resident set ~14MB fits aggregate L2 (was ~20MB borderline); lower L2
// miss rate shortens the staging drain that R13 showed is the binding term.
//
// ws (68 MiB; >=69.4 MiB proven available in R5):
//   u [0,32M) (K2->K5; out2 alias K5->K6), vT [32M,64M), o_wb [64M,68M)
// d_out (33.55 MB fp32) dead-interval scratch:
//   xn [0,16M) P->K2 ; uv_wb [16M,24.65M) ; baseb [24.65M,26.25M) ; tables
//   [26.25M,26.5M) ; then qb [0,2M) kb [2M,4M) K3->K4 ; km [4M,12M) K4->K5.
//   All dead before K6 writes d_out.

typedef __bf16 bf16_t;
typedef __bf16 bf16x4 __attribute__((ext_vector_type(4)));
typedef __bf16 bf16x8 __attribute__((ext_vector_type(8)));
typedef float  f32x4  __attribute__((ext_vector_type(4)));

__device__ __forceinline__ void async16(const void* g, void* l) {
  __builtin_amdgcn_global_load_lds(
      (const __attribute__((address_space(1))) void*)g,
      (__attribute__((address_space(3))) void*)l, 16, 0, 0);
}

// ---------------- sentinel (ws guard diagnostics) ----------------
__global__ __launch_bounds__(256) void fill_const(float* __restrict__ out,
                                                  float val, int n) {
  int i = blockIdx.x * 256 + threadIdx.x;
  if (i < n) out[i] = val;
}

// ---------------- P: fused prologue ----------------
// blocks [0,128):        rope cos/sin tables (512x64, fp64 ref-exact path)
// blocks [128,4352):     cvt uv_w -> bf16   (1,081,344 f32x4)
// blocks [4352,6400):    cvt o_w -> bf16    (524,288 f32x4)
// blocks [6400,14592):   layernorm row = bid-6400
__global__ __launch_bounds__(256) void prologue(
    const float* __restrict__ x, const float* __restrict__ ln_w,
    const float* __restrict__ ln_b, bf16_t* __restrict__ xn,
    const float* __restrict__ uv_w, bf16_t* __restrict__ uv_wb,
    const float* __restrict__ o_w, bf16_t* __restrict__ o_wb,
    float* __restrict__ cosT, float* __restrict__ sinT) {
  const int bid = blockIdx.x;
  const int tid = threadIdx.x;
  if (bid < 128) {
    int idx = bid * 256 + tid;   // 512*64
    int n = idx >> 6, j = idx & 63;
    float invf = (float)pow(10000.0, (double)j * (1.0 / 64.0));
    float angf = (float)n * invf;
    cosT[idx] = (float)cos((double)angf);
    sinT[idx] = (float)sin((double)angf);
  } else if (bid < 6400) {
    const float* in = (bid < 4352) ? uv_w : o_w;
    bf16_t* out = (bid < 4352) ? uv_wb : o_wb;
    int i = (bid - ((bid < 4352) ? 128 : 4352)) * 256 + tid;
    f32x4 v = ((const f32x4*)in)[i];
    bf16x4 o;
    o[0] = (__bf16)v[0]; o[1] = (__bf16)v[1];
    o[2] = (__bf16)v[2]; o[3] = (__bf16)v[3];
    ((bf16x4*)out)[i] = o;
  } else {
    int row = bid - 6400;
    f32x4 v = *(const f32x4*)(x + (size_t)row * 1024 + tid * 4);
    float s = v[0] + v[1] + v[2] + v[3];
    float s2 = v[0]*v[0] + v[1]*v[1] + v[2]*v[2] + v[3]*v[3];
    for (int o = 32; o > 0; o >>= 1) {
      s += __shfl_down(s, o);
      s2 += __shfl_down(s2, o);
    }
    __shared__ float ps[4], ps2[4];
    if ((tid & 63) == 0) { ps[tid >> 6] = s; ps2[tid >> 6] = s2; }
    __syncthreads();
    float st = ps[0] + ps[1] + ps[2] + ps[3];
    float st2 = ps2[0] + ps2[1] + ps2[2] + ps2[3];
    float mean = st * (1.f / 1024.f);
    float var = st2 * (1.f / 1024.f) - mean * mean;
    float inv = 1.f / sqrtf(var + 1e-5f);
    bf16x4 o4;
    for (int i = 0; i < 4; i++) {
      float wn = ln_w[tid * 4 + i], bn = ln_b[tid * 4 + i];
      o4[i] = (__bf16)((v[i] - mean) * inv * wn + bn);
    }
    *(bf16x4*)(xn + (size_t)row * 1024 + tid * 4) = o4;
  }
}

// ---------------- K3: gamma/beta + rope -> q, k ----------------
__global__ __launch_bounds__(128) void rope_qk(const bf16_t* __restrict__ baseb,
                                               const float* __restrict__ gamma,
                                               const float* __restrict__ beta,
                                               const float* __restrict__ cosT,
                                               const float* __restrict__ sinT,
                                               bf16_t* __restrict__ q,
                                               bf16_t* __restrict__ k) {
  int m = blockIdx.x;        // b*512 + n
  int n = m & 511;
  int s = threadIdx.x;       // 0..127
  float base = (float)baseb[(size_t)m * 128 + s];
  __shared__ float t[2][128];
  t[0][s] = base * gamma[s] + beta[s];
  t[1][s] = base * gamma[128 + s] + beta[128 + s];
  __syncthreads();
  int j = s & 63;
  float c = cosT[n * 64 + j], sn = sinT[n * 64 + j];
  for (int h = 0; h < 2; h++) {
    float x1 = t[h][j], x2 = t[h][64 + j];
    float r = (s < 64) ? (x1 * c - x2 * sn) : (x2 * c + x1 * sn);
    bf16_t* dst = h == 0 ? q : k;
    dst[(size_t)m * 128 + s] = (__bf16)r;
  }
}

// ------- epilogues: f32x4 = C rows m0..m0+3, col n. NaN-scrub clamps. ------
struct EpiUV {   // + uv_b, silu -> u | vT (transposed) | base
  const float* uv_b;
  bf16_t* u;
  bf16_t* vT;      // [16][2048][512]
  bf16_t* baseb;
  __device__ void operator()(int b, int m0, int n, f32x4 a4) const {
    float bn = uv_b[n];
    bf16_t s[4];
#pragma unroll
    for (int r = 0; r < 4; r++) {
      float xv = a4[r] + bn;
      // silu via v_rcp_f32 (R10): '/' expands to div_scale/fmas/fixup.
      float sv = xv * __builtin_amdgcn_rcpf(1.f + __expf(-xv));
      sv = fminf(fmaxf(sv, -100.f), 100.f);
      s[r] = (__bf16)sv;
    }
    if (n < 2048) {
#pragma unroll
      for (int r = 0; r < 4; r++) u[(size_t)(m0 + r) * 2048 + n] = s[r];
    } else if (n < 4096) {
      // transpose store: 4 consecutive nseq for fixed e -> one 8B store
      int bb = m0 >> 9, ns = m0 & 511;
      bf16x4 p; p[0] = s[0]; p[1] = s[1]; p[2] = s[2]; p[3] = s[3];
      *(bf16x4*)(vT + ((size_t)bb * 2048 + (n - 2048)) * 512 + ns) = p;
    } else {
#pragma unroll
      for (int r = 0; r < 4; r++)
        baseb[(size_t)(m0 + r) * 128 + (n - 4096)] = s[r];
    }
  }
};
struct EpiQK {   // clamp(relu(acc/512 + w_rel[511+j-i]))^2 -> km
  const float* w_rel;
  bf16_t* km;
  __device__ void operator()(int b, int i0, int j, f32x4 a4) const {
#pragma unroll
    for (int r = 0; r < 4; r++) {
      float bias = w_rel[511 + j - (i0 + r)];
      float t = fmaxf(a4[r] * (1.f / 512.f) + bias, 0.f);
      t = fminf(t, 100.f);
      km[((size_t)b * 512 + i0 + r) * 512 + j] = (__bf16)(t * t);
    }
  }
};
struct EpiAttn { // clamp(acc * u) -> out2 (out2 aliases u element-exactly)
  const bf16_t* u;
  bf16_t* out2;
  __device__ void operator()(int b, int i0, int e, f32x4 a4) const {
#pragma unroll
    for (int r = 0; r < 4; r++) {
      size_t m = (size_t)b * 512 + i0 + r;
      float uu = (float)u[m * 2048 + e];
      float rr = a4[r] * uu;
      rr = fminf(fmaxf(rr, -1e6f), 1e6f);
      out2[m * 2048 + e] = (__bf16)rr;
    }
  }
};
struct EpiOut {  // clamp(acc + o_b + shortcut) -> fp32 out
  const float* o_b;
  const float* x;
  float* out;
  __device__ void operator()(int b, int m0, int d, f32x4 a4) const {
    float ob = o_b[d];
#pragma unroll
    for (int r = 0; r < 4; r++) {
      long idx = (long)(m0 + r) * 1024 + d;
      float rr = a4[r] + ob + x[idx];
      rr = fminf(fmaxf(rr, -1e5f), 1e5f);
      out[idx] = rr;
    }
  }
};

// -------- templated NT GEMM (BK=32 dbuf, stage-after-barrier pipeline) -----
// C[m][n] = sum_k A[m][k]*B[n][k]; A,B bf16 K-contiguous. Block tile
// (MFR*32) x 128, 256 threads (4 waves 2x2); wave computes (MFR*16) x 64.
// BK=32. LDS: 2 buffers x {A MROWS*64B | B 8KB}. MFR=4: 32KB total.
// R14: block mapping x->tileN, y->tileM (consecutive blocks share the A
// panel, stream B; K2 resident set ~14MB fits aggregate L2).
// Layout per matrix: 128B lines = 2 rows x 32 bf16. Within line L, 16B slot
// s holds source chunk g = s^(L&7) (row 2L+(g>>2), k-chunk g&3). Fragment
// read: 2-way bank alias max (free; R6-class layout, measured 0 conflicts).
// Loop: __syncthreads (drains tile-t loads, issued ONE compute phase ago);
// stage(t+1 -> buf^1); compute(buf). One barrier per K-32. PROVEN R13 --
// sync structure frozen (counted-vmcnt/raw-barrier variants failed 3x).
template <int MFR, typename Epi>
__global__ __launch_bounds__(256, 2)
void gemm_nt(const bf16_t* __restrict__ A, const bf16_t* __restrict__ Bm,
             int lda, int ldb, int K, long sAz, long sBz, Epi epi) {
  constexpr int MROWS = MFR * 32;
  constexpr int ABYTES = MROWS * 64;      // A region per buffer
  constexpr int BUFB = ABYTES + 8192;     // + B region (128 rows x 64B)
  constexpr int NA = MROWS / 64;          // A staging iters (1KB blocks /4 waves)
  __shared__ __align__(16) char smem[2 * BUFB];
  const int tid = threadIdx.x;
  const int lane = tid & 63;
  const int wid = tid >> 6;
  const int wm = wid & 1, wn = wid >> 1;
  const int quad = lane >> 4, col16 = lane & 15;
  const int bz = blockIdx.z;
  const int tileM = blockIdx.y * MROWS;   // R14: y -> M
  const int tileN = blockIdx.x * 128;     // R14: x -> N
  const bf16_t* Ab = A + (size_t)bz * sAz;
  const bf16_t* Bb = Bm + (size_t)bz * sBz;
  const int NT = K >> 5;                  // K-tiles of 32

  // Staging geometry: chunk c = u*64 + lane (u = i*4+wid wave-uniform 1KB id);
  // line L = c>>3, slot s = c&7; source g = s^(L&7) -> g is u-independent:
  // g = (lane&7) ^ ((lane>>3)&7). Source row = u*16 + 2*(lane>>3) + (g>>2).
  const int g = (lane & 7) ^ ((lane >> 3) & 7);
  const int rowb = 2 * (lane >> 3) + (g >> 2);
  const int kcb = (g & 3) * 8;            // element offset within row
  unsigned oA[NA], oB[2];
#pragma unroll
  for (int i = 0; i < NA; i++) {
    int u = i * 4 + wid;
    oA[i] = (unsigned)((tileM + u * 16 + rowb) * lda + kcb);
  }
#pragma unroll
  for (int i = 0; i < 2; i++) {
    int u = i * 4 + wid;
    oB[i] = (unsigned)((tileN + u * 16 + rowb) * ldb + kcb);
  }

  // Fragment byte offsets (row ml/nl, k-chunk quad).
  int offA[MFR], offB[4];
#pragma unroll
  for (int mt = 0; mt < MFR; mt++) {
    int ml = wm * (MFR * 16) + mt * 16 + col16;
    int L = ml >> 1, gg = (ml & 1) * 4 + quad;
    offA[mt] = L * 128 + ((gg ^ (L & 7)) * 16);
  }
#pragma unroll
  for (int nt = 0; nt < 4; nt++) {
    int nl = wn * 64 + nt * 16 + col16;
    int L = nl >> 1, gg = (nl & 1) * 4 + quad;
    offB[nt] = L * 128 + ((gg ^ (L & 7)) * 16);
  }

  auto stage = [&](int kt, int p) {       // (NA+2) async16/thread
    char* base = (char*)smem + p * BUFB;
    const unsigned ko = (unsigned)kt * 32;
#pragma unroll
    for (int i = 0; i < NA; i++)
      async16(Ab + oA[i] + ko, base + (i * 4 + wid) * 1024);
#pragma unroll
    for (int i = 0; i < 2; i++)
      async16(Bb + oB[i] + ko, base + ABYTES + (i * 4 + wid) * 1024);
  };

  f32x4 acc[MFR][4] = {};

  stage(0, 0);
#pragma unroll 2
  for (int t = 0; t < NT; t++) {
    __syncthreads();                      // tile-t loads drained (1 phase old)
    if (t + 1 < NT) stage(t + 1, (t + 1) & 1);
    const char* sA = (const char*)smem + (t & 1) * BUFB;
    const char* sB = sA + ABYTES;
    bf16x8 af[MFR], bfr[4];
#pragma unroll
    for (int mt = 0; mt < MFR; mt++) af[mt] = *(const bf16x8*)(sA + offA[mt]);
#pragma unroll
    for (int nt = 0; nt < 4; nt++) bfr[nt] = *(const bf16x8*)(sB + offB[nt]);
#pragma unroll
    for (int mt = 0; mt < MFR; mt++)
#pragma unroll
      for (int nt = 0; nt < 4; nt++)
        acc[mt][nt] = __builtin_amdgcn_mfma_f32_16x16x32_bf16(
            af[mt], bfr[nt], acc[mt][nt], 0, 0, 0);
  }

#pragma unroll
  for (int mt = 0; mt < MFR; mt++) {
    int gm = tileM + wm * (MFR * 16) + mt * 16 + quad * 4;
#pragma unroll
    for (int nt = 0; nt < 4; nt++) {
      int gn = tileN + wn * 64 + nt * 16 + col16;
      epi(bz, gm, gn, acc[mt][nt]);
    }
  }
}

extern "C" void kernel_launch(void* const* d_in, const int* in_sizes, int n_in,
                              void* d_out, int out_size, void* d_ws, size_t ws_size,
                              hipStream_t stream) {
  const float* x = (const float*)d_in[0];
  const float* ln_w = (const float*)d_in[1];
  const float* ln_b = (const float*)d_in[2];
  const float* uv_w = (const float*)d_in[3];
  const float* uv_b = (const float*)d_in[4];
  const float* gamma = (const float*)d_in[5];
  const float* beta = (const float*)d_in[6];
  const float* o_w = (const float*)d_in[7];
  const float* o_b = (const float*)d_in[8];
  const float* w_rel = (const float*)d_in[9];
  float* out = (float*)d_out;

  const int NOUT = 8388608;
  const size_t WS_NEEDED = 71303168;   // 68 MiB (>=69.4 MiB proven in R5)
  if (ws_size < WS_NEEDED) {
    float wsMiB = (float)(ws_size >> 20);
    fill_const<<<dim3(32768), dim3(256), 0, stream>>>(out, 1000.f + wsMiB, NOUT);
    return;
  }

  // ws: u [0,32M) (out2 alias), vT [32M,64M), o_wb [64M,68M)
  char* ws = (char*)d_ws;
  bf16_t* u = (bf16_t*)(ws + 0);
  bf16_t* out2 = u;
  bf16_t* vT = (bf16_t*)(ws + 33554432);
  bf16_t* o_wb = (bf16_t*)(ws + 67108864);
  // d_out dead-interval scratch (33.55 MB fp32 region):
  char* ob = (char*)d_out;
  bf16_t* xn = (bf16_t*)ob;                       // [0, 16,777,216)
  bf16_t* uv_wb = (bf16_t*)(ob + 16777216);       // [16,777,216, 25,427,968)
  bf16_t* baseb = (bf16_t*)(ob + 25427968);       // [25,427,968, 27,525,120)
  float* cosT = (float*)(ob + 27525120);          // [27,525,120, 27,656,192)
  float* sinT = (float*)(ob + 27656192);          // [27,656,192, 27,787,264)
  bf16_t* qb = (bf16_t*)ob;                       // [0, 2M)   K3->K4
  bf16_t* kb = (bf16_t*)(ob + 2097152);           // [2M, 4M)  K3->K4
  bf16_t* km = (bf16_t*)(ob + 4194304);           // [4M, 12M) K4->K5

  // P: fused prologue (rope tables | cvt uv | cvt o | layernorm)
  prologue<<<dim3(14592), dim3(256), 0, stream>>>(
      x, ln_w, ln_b, xn, uv_w, uv_wb, o_w, o_wb, cosT, sinT);
  // K2: silu(xn @ uv_wb^T + uv_b) -> u | vT | base: M=8192, N=4224, K=1024
  gemm_nt<4><<<dim3(33, 64, 1), dim3(256), 0, stream>>>(
      xn, uv_wb, 1024, 1024, 1024, 0L, 0L, EpiUV{uv_b, u, vT, baseb});
  rope_qk<<<dim3(8192), dim3(128), 0, stream>>>(baseb, gamma, beta, cosT, sinT, qb, kb);
  // K4: km = relu(q@k^T/512 + bias)^2: per batch M=N=512, K=128
  gemm_nt<4><<<dim3(4, 4, 16), dim3(256), 0, stream>>>(
      qb, kb, 128, 128, 128, (long)512 * 128, (long)512 * 128, EpiQK{w_rel, km});
  // K5: out2 = u * (km @ v): per batch M=512, N=2048, K=512
  gemm_nt<8><<<dim3(16, 2, 16), dim3(256), 0, stream>>>(
      km, vT, 512, 512, 512, (long)512 * 512, (long)2048 * 512, EpiAttn{u, out2});
  // K6: out = out2 @ o_wb^T + o_b + x: M=8192, N=1024, K=2048
  gemm_nt<4><<<dim3(8, 64, 1), dim3(256), 0, stream>>>(
      out2, o_wb, 2048, 2048, 2048, 0L, 0L, EpiOut{o_b, x, out});
}

// Round 8
// 325.414 us; speedup vs baseline: 1.0527x; 1.0527x over previous
//
#include <hip/hip_runtime.h>
#include <hip/hip_bf16.h>

// GateAttentionUnit. B=16, N=512, D=1024, E=2048, S=128, F=2E+S=4224.
// CONFIRMED: all 10 inputs fp32, output fp32. Internal compute bf16 MFMA.
//
// Pipeline:
//   P  prologue (fused): rope tables | uv_w->bf16 | o_w->bf16 | layernorm
//   K2 gemm<4,EpiUV>: silu(xn @ uv_wb^T + uv_b) -> u | vT | base   [8192 x 4224]
//   K3 rope_qk:    q,k = rope(base*gamma+beta) (d_out scratch)     [8192 x 128]
//   K4 gemm<4,EpiQK>:   km = relu(q@k^T/512 + relpos)^2 (d_out)    [16][512][512]
//   K5 gemm<8,EpiAttn>: out2 = u * (km @ vT^T), out2 aliases u     [8192 x 2048]
//   K6 gemm<4,EpiOut>:  out = out2 @ o_wb^T + o_b + x  (fp32 out)  [8192 x 1024]
//
// R14 -> R15: block mapping REVERTED to R13-proven x->tileM, y->tileN.
// R14 evidence: x->tileN made consecutive blocks stream all of B (8.65MB)
// through each XCD's private 4MB L2 -> FETCH 65->262 GB-units (4x), K2
// 107->119. Correct rule: small shared panel (B, 256KB) on the fast-varying
// dim; L3 (256MB) absorbs the big streamed operand (A). Fused prologue KEPT
// (this round isolates it: R15 vs R13 = fusion only). GEMM core frozen
// (R13-verified: BK=32 dbuf, stage-after-barrier; 663 TF = documented
// 2-phase ceiling; 3 sync rewrites + 2 mapping/tile probes all confirmed).
//
// ws (68 MiB; >=69.4 MiB proven available in R5):
//   u [0,32M) (K2->K5; out2 alias K5->K6), vT [32M,64M), o_wb [64M,68M)
// d_out (33.55 MB fp32) dead-interval scratch:
//   xn [0,16M) P->K2 ; uv_wb [16M,24.65M) ; baseb [24.65M,26.25M) ; tables
//   [26.25M,26.5M) ; then qb [0,2M) kb [2M,4M) K3->K4 ; km [4M,12M) K4->K5.
//   All dead before K6 writes d_out.

typedef __bf16 bf16_t;
typedef __bf16 bf16x4 __attribute__((ext_vector_type(4)));
typedef __bf16 bf16x8 __attribute__((ext_vector_type(8)));
typedef float  f32x4  __attribute__((ext_vector_type(4)));

__device__ __forceinline__ void async16(const void* g, void* l) {
  __builtin_amdgcn_global_load_lds(
      (const __attribute__((address_space(1))) void*)g,
      (__attribute__((address_space(3))) void*)l, 16, 0, 0);
}

// ---------------- sentinel (ws guard diagnostics) ----------------
__global__ __launch_bounds__(256) void fill_const(float* __restrict__ out,
                                                  float val, int n) {
  int i = blockIdx.x * 256 + threadIdx.x;
  if (i < n) out[i] = val;
}

// ---------------- P: fused prologue ----------------
// blocks [0,128):        rope cos/sin tables (512x64, fp64 ref-exact path)
// blocks [128,4352):     cvt uv_w -> bf16   (1,081,344 f32x4)
// blocks [4352,6400):    cvt o_w -> bf16    (524,288 f32x4)
// blocks [6400,14592):   layernorm row = bid-6400
__global__ __launch_bounds__(256) void prologue(
    const float* __restrict__ x, const float* __restrict__ ln_w,
    const float* __restrict__ ln_b, bf16_t* __restrict__ xn,
    const float* __restrict__ uv_w, bf16_t* __restrict__ uv_wb,
    const float* __restrict__ o_w, bf16_t* __restrict__ o_wb,
    float* __restrict__ cosT, float* __restrict__ sinT) {
  const int bid = blockIdx.x;
  const int tid = threadIdx.x;
  if (bid < 128) {
    int idx = bid * 256 + tid;   // 512*64
    int n = idx >> 6, j = idx & 63;
    float invf = (float)pow(10000.0, (double)j * (1.0 / 64.0));
    float angf = (float)n * invf;
    cosT[idx] = (float)cos((double)angf);
    sinT[idx] = (float)sin((double)angf);
  } else if (bid < 6400) {
    const float* in = (bid < 4352) ? uv_w : o_w;
    bf16_t* out = (bid < 4352) ? uv_wb : o_wb;
    int i = (bid - ((bid < 4352) ? 128 : 4352)) * 256 + tid;
    f32x4 v = ((const f32x4*)in)[i];
    bf16x4 o;
    o[0] = (__bf16)v[0]; o[1] = (__bf16)v[1];
    o[2] = (__bf16)v[2]; o[3] = (__bf16)v[3];
    ((bf16x4*)out)[i] = o;
  } else {
    int row = bid - 6400;
    f32x4 v = *(const f32x4*)(x + (size_t)row * 1024 + tid * 4);
    float s = v[0] + v[1] + v[2] + v[3];
    float s2 = v[0]*v[0] + v[1]*v[1] + v[2]*v[2] + v[3]*v[3];
    for (int o = 32; o > 0; o >>= 1) {
      s += __shfl_down(s, o);
      s2 += __shfl_down(s2, o);
    }
    __shared__ float ps[4], ps2[4];
    if ((tid & 63) == 0) { ps[tid >> 6] = s; ps2[tid >> 6] = s2; }
    __syncthreads();
    float st = ps[0] + ps[1] + ps[2] + ps[3];
    float st2 = ps2[0] + ps2[1] + ps2[2] + ps2[3];
    float mean = st * (1.f / 1024.f);
    float var = st2 * (1.f / 1024.f) - mean * mean;
    float inv = 1.f / sqrtf(var + 1e-5f);
    bf16x4 o4;
    for (int i = 0; i < 4; i++) {
      float wn = ln_w[tid * 4 + i], bn = ln_b[tid * 4 + i];
      o4[i] = (__bf16)((v[i] - mean) * inv * wn + bn);
    }
    *(bf16x4*)(xn + (size_t)row * 1024 + tid * 4) = o4;
  }
}

// ---------------- K3: gamma/beta + rope -> q, k ----------------
__global__ __launch_bounds__(128) void rope_qk(const bf16_t* __restrict__ baseb,
                                               const float* __restrict__ gamma,
                                               const float* __restrict__ beta,
                                               const float* __restrict__ cosT,
                                               const float* __restrict__ sinT,
                                               bf16_t* __restrict__ q,
                                               bf16_t* __restrict__ k) {
  int m = blockIdx.x;        // b*512 + n
  int n = m & 511;
  int s = threadIdx.x;       // 0..127
  float base = (float)baseb[(size_t)m * 128 + s];
  __shared__ float t[2][128];
  t[0][s] = base * gamma[s] + beta[s];
  t[1][s] = base * gamma[128 + s] + beta[128 + s];
  __syncthreads();
  int j = s & 63;
  float c = cosT[n * 64 + j], sn = sinT[n * 64 + j];
  for (int h = 0; h < 2; h++) {
    float x1 = t[h][j], x2 = t[h][64 + j];
    float r = (s < 64) ? (x1 * c - x2 * sn) : (x2 * c + x1 * sn);
    bf16_t* dst = h == 0 ? q : k;
    dst[(size_t)m * 128 + s] = (__bf16)r;
  }
}

// ------- epilogues: f32x4 = C rows m0..m0+3, col n. NaN-scrub clamps. ------
struct EpiUV {   // + uv_b, silu -> u | vT (transposed) | base
  const float* uv_b;
  bf16_t* u;
  bf16_t* vT;      // [16][2048][512]
  bf16_t* baseb;
  __device__ void operator()(int b, int m0, int n, f32x4 a4) const {
    float bn = uv_b[n];
    bf16_t s[4];
#pragma unroll
    for (int r = 0; r < 4; r++) {
      float xv = a4[r] + bn;
      // silu via v_rcp_f32 (R10): '/' expands to div_scale/fmas/fixup.
      float sv = xv * __builtin_amdgcn_rcpf(1.f + __expf(-xv));
      sv = fminf(fmaxf(sv, -100.f), 100.f);
      s[r] = (__bf16)sv;
    }
    if (n < 2048) {
#pragma unroll
      for (int r = 0; r < 4; r++) u[(size_t)(m0 + r) * 2048 + n] = s[r];
    } else if (n < 4096) {
      // transpose store: 4 consecutive nseq for fixed e -> one 8B store
      int bb = m0 >> 9, ns = m0 & 511;
      bf16x4 p; p[0] = s[0]; p[1] = s[1]; p[2] = s[2]; p[3] = s[3];
      *(bf16x4*)(vT + ((size_t)bb * 2048 + (n - 2048)) * 512 + ns) = p;
    } else {
#pragma unroll
      for (int r = 0; r < 4; r++)
        baseb[(size_t)(m0 + r) * 128 + (n - 4096)] = s[r];
    }
  }
};
struct EpiQK {   // clamp(relu(acc/512 + w_rel[511+j-i]))^2 -> km
  const float* w_rel;
  bf16_t* km;
  __device__ void operator()(int b, int i0, int j, f32x4 a4) const {
#pragma unroll
    for (int r = 0; r < 4; r++) {
      float bias = w_rel[511 + j - (i0 + r)];
      float t = fmaxf(a4[r] * (1.f / 512.f) + bias, 0.f);
      t = fminf(t, 100.f);
      km[((size_t)b * 512 + i0 + r) * 512 + j] = (__bf16)(t * t);
    }
  }
};
struct EpiAttn { // clamp(acc * u) -> out2 (out2 aliases u element-exactly)
  const bf16_t* u;
  bf16_t* out2;
  __device__ void operator()(int b, int i0, int e, f32x4 a4) const {
#pragma unroll
    for (int r = 0; r < 4; r++) {
      size_t m = (size_t)b * 512 + i0 + r;
      float uu = (float)u[m * 2048 + e];
      float rr = a4[r] * uu;
      rr = fminf(fmaxf(rr, -1e6f), 1e6f);
      out2[m * 2048 + e] = (__bf16)rr;
    }
  }
};
struct EpiOut {  // clamp(acc + o_b + shortcut) -> fp32 out
  const float* o_b;
  const float* x;
  float* out;
  __device__ void operator()(int b, int m0, int d, f32x4 a4) const {
    float ob = o_b[d];
#pragma unroll
    for (int r = 0; r < 4; r++) {
      long idx = (long)(m0 + r) * 1024 + d;
      float rr = a4[r] + ob + x[idx];
      rr = fminf(fmaxf(rr, -1e5f), 1e5f);
      out[idx] = rr;
    }
  }
};

// -------- templated NT GEMM (BK=32 dbuf, stage-after-barrier pipeline) -----
// C[m][n] = sum_k A[m][k]*B[n][k]; A,B bf16 K-contiguous. Block tile
// (MFR*32) x 128, 256 threads (4 waves 2x2); wave computes (MFR*16) x 64.
// BK=32. LDS: 2 buffers x {A MROWS*64B | B 8KB}. MFR=4: 32KB total.
// Block mapping: x->tileM (fast), y->tileN -- consecutive blocks share the
// SMALL B panel (fits per-XCD L2); L3 absorbs streamed-A re-reads. (R14
// proved the swap costs 4x FETCH + 12% time. Do not swap again.)
// Layout per matrix: 128B lines = 2 rows x 32 bf16. Within line L, 16B slot
// s holds source chunk g = s^(L&7) (row 2L+(g>>2), k-chunk g&3). Fragment
// read: 2-way bank alias max (free; R6-class layout, measured 0 conflicts).
// Loop: __syncthreads (drains tile-t loads, issued ONE compute phase ago);
// stage(t+1 -> buf^1); compute(buf). One barrier per K-32. PROVEN R13 --
// sync structure frozen (counted-vmcnt/raw-barrier variants failed 3x).
template <int MFR, typename Epi>
__global__ __launch_bounds__(256, 2)
void gemm_nt(const bf16_t* __restrict__ A, const bf16_t* __restrict__ Bm,
             int lda, int ldb, int K, long sAz, long sBz, Epi epi) {
  constexpr int MROWS = MFR * 32;
  constexpr int ABYTES = MROWS * 64;      // A region per buffer
  constexpr int BUFB = ABYTES + 8192;     // + B region (128 rows x 64B)
  constexpr int NA = MROWS / 64;          // A staging iters (1KB blocks /4 waves)
  __shared__ __align__(16) char smem[2 * BUFB];
  const int tid = threadIdx.x;
  const int lane = tid & 63;
  const int wid = tid >> 6;
  const int wm = wid & 1, wn = wid >> 1;
  const int quad = lane >> 4, col16 = lane & 15;
  const int bz = blockIdx.z;
  const int tileM = blockIdx.x * MROWS;   // x -> M (R13-proven)
  const int tileN = blockIdx.y * 128;     // y -> N
  const bf16_t* Ab = A + (size_t)bz * sAz;
  const bf16_t* Bb = Bm + (size_t)bz * sBz;
  const int NT = K >> 5;                  // K-tiles of 32

  // Staging geometry: chunk c = u*64 + lane (u = i*4+wid wave-uniform 1KB id);
  // line L = c>>3, slot s = c&7; source g = s^(L&7) -> g is u-independent:
  // g = (lane&7) ^ ((lane>>3)&7). Source row = u*16 + 2*(lane>>3) + (g>>2).
  const int g = (lane & 7) ^ ((lane >> 3) & 7);
  const int rowb = 2 * (lane >> 3) + (g >> 2);
  const int kcb = (g & 3) * 8;            // element offset within row
  unsigned oA[NA], oB[2];
#pragma unroll
  for (int i = 0; i < NA; i++) {
    int u = i * 4 + wid;
    oA[i] = (unsigned)((tileM + u * 16 + rowb) * lda + kcb);
  }
#pragma unroll
  for (int i = 0; i < 2; i++) {
    int u = i * 4 + wid;
    oB[i] = (unsigned)((tileN + u * 16 + rowb) * ldb + kcb);
  }

  // Fragment byte offsets (row ml/nl, k-chunk quad).
  int offA[MFR], offB[4];
#pragma unroll
  for (int mt = 0; mt < MFR; mt++) {
    int ml = wm * (MFR * 16) + mt * 16 + col16;
    int L = ml >> 1, gg = (ml & 1) * 4 + quad;
    offA[mt] = L * 128 + ((gg ^ (L & 7)) * 16);
  }
#pragma unroll
  for (int nt = 0; nt < 4; nt++) {
    int nl = wn * 64 + nt * 16 + col16;
    int L = nl >> 1, gg = (nl & 1) * 4 + quad;
    offB[nt] = L * 128 + ((gg ^ (L & 7)) * 16);
  }

  auto stage = [&](int kt, int p) {       // (NA+2) async16/thread
    char* base = (char*)smem + p * BUFB;
    const unsigned ko = (unsigned)kt * 32;
#pragma unroll
    for (int i = 0; i < NA; i++)
      async16(Ab + oA[i] + ko, base + (i * 4 + wid) * 1024);
#pragma unroll
    for (int i = 0; i < 2; i++)
      async16(Bb + oB[i] + ko, base + ABYTES + (i * 4 + wid) * 1024);
  };

  f32x4 acc[MFR][4] = {};

  stage(0, 0);
#pragma unroll 2
  for (int t = 0; t < NT; t++) {
    __syncthreads();                      // tile-t loads drained (1 phase old)
    if (t + 1 < NT) stage(t + 1, (t + 1) & 1);
    const char* sA = (const char*)smem + (t & 1) * BUFB;
    const char* sB = sA + ABYTES;
    bf16x8 af[MFR], bfr[4];
#pragma unroll
    for (int mt = 0; mt < MFR; mt++) af[mt] = *(const bf16x8*)(sA + offA[mt]);
#pragma unroll
    for (int nt = 0; nt < 4; nt++) bfr[nt] = *(const bf16x8*)(sB + offB[nt]);
#pragma unroll
    for (int mt = 0; mt < MFR; mt++)
#pragma unroll
      for (int nt = 0; nt < 4; nt++)
        acc[mt][nt] = __builtin_amdgcn_mfma_f32_16x16x32_bf16(
            af[mt], bfr[nt], acc[mt][nt], 0, 0, 0);
  }

#pragma unroll
  for (int mt = 0; mt < MFR; mt++) {
    int gm = tileM + wm * (MFR * 16) + mt * 16 + quad * 4;
#pragma unroll
    for (int nt = 0; nt < 4; nt++) {
      int gn = tileN + wn * 64 + nt * 16 + col16;
      epi(bz, gm, gn, acc[mt][nt]);
    }
  }
}

extern "C" void kernel_launch(void* const* d_in, const int* in_sizes, int n_in,
                              void* d_out, int out_size, void* d_ws, size_t ws_size,
                              hipStream_t stream) {
  const float* x = (const float*)d_in[0];
  const float* ln_w = (const float*)d_in[1];
  const float* ln_b = (const float*)d_in[2];
  const float* uv_w = (const float*)d_in[3];
  const float* uv_b = (const float*)d_in[4];
  const float* gamma = (const float*)d_in[5];
  const float* beta = (const float*)d_in[6];
  const float* o_w = (const float*)d_in[7];
  const float* o_b = (const float*)d_in[8];
  const float* w_rel = (const float*)d_in[9];
  float* out = (float*)d_out;

  const int NOUT = 8388608;
  const size_t WS_NEEDED = 71303168;   // 68 MiB (>=69.4 MiB proven in R5)
  if (ws_size < WS_NEEDED) {
    float wsMiB = (float)(ws_size >> 20);
    fill_const<<<dim3(32768), dim3(256), 0, stream>>>(out, 1000.f + wsMiB, NOUT);
    return;
  }

  // ws: u [0,32M) (out2 alias), vT [32M,64M), o_wb [64M,68M)
  char* ws = (char*)d_ws;
  bf16_t* u = (bf16_t*)(ws + 0);
  bf16_t* out2 = u;
  bf16_t* vT = (bf16_t*)(ws + 33554432);
  bf16_t* o_wb = (bf16_t*)(ws + 67108864);
  // d_out dead-interval scratch (33.55 MB fp32 region):
  char* ob = (char*)d_out;
  bf16_t* xn = (bf16_t*)ob;                       // [0, 16,777,216)
  bf16_t* uv_wb = (bf16_t*)(ob + 16777216);       // [16,777,216, 25,427,968)
  bf16_t* baseb = (bf16_t*)(ob + 25427968);       // [25,427,968, 27,525,120)
  float* cosT = (float*)(ob + 27525120);          // [27,525,120, 27,656,192)
  float* sinT = (float*)(ob + 27656192);          // [27,656,192, 27,787,264)
  bf16_t* qb = (bf16_t*)ob;                       // [0, 2M)   K3->K4
  bf16_t* kb = (bf16_t*)(ob + 2097152);           // [2M, 4M)  K3->K4
  bf16_t* km = (bf16_t*)(ob + 4194304);           // [4M, 12M) K4->K5

  // P: fused prologue (rope tables | cvt uv | cvt o | layernorm)
  prologue<<<dim3(14592), dim3(256), 0, stream>>>(
      x, ln_w, ln_b, xn, uv_w, uv_wb, o_w, o_wb, cosT, sinT);
  // K2: silu(xn @ uv_wb^T + uv_b) -> u | vT | base: M=8192, N=4224, K=1024
  gemm_nt<4><<<dim3(64, 33, 1), dim3(256), 0, stream>>>(
      xn, uv_wb, 1024, 1024, 1024, 0L, 0L, EpiUV{uv_b, u, vT, baseb});
  rope_qk<<<dim3(8192), dim3(128), 0, stream>>>(baseb, gamma, beta, cosT, sinT, qb, kb);
  // K4: km = relu(q@k^T/512 + bias)^2: per batch M=N=512, K=128
  gemm_nt<4><<<dim3(4, 4, 16), dim3(256), 0, stream>>>(
      qb, kb, 128, 128, 128, (long)512 * 128, (long)512 * 128, EpiQK{w_rel, km});
  // K5: out2 = u * (km @ v): per batch M=512, N=2048, K=512
  gemm_nt<8><<<dim3(2, 16, 16), dim3(256), 0, stream>>>(
      km, vT, 512, 512, 512, (long)512 * 512, (long)2048 * 512, EpiAttn{u, out2});
  // K6: out = out2 @ o_wb^T + o_b + x: M=8192, N=1024, K=2048
  gemm_nt<4><<<dim3(64, 8, 1), dim3(256), 0, stream>>>(
      out2, o_wb, 2048, 2048, 2048, 0L, 0L, EpiOut{o_b, x, out});
}

// Round 9
// 324.947 us; speedup vs baseline: 1.0542x; 1.0014x over previous
//
#include <hip/hip_runtime.h>
#include <hip/hip_bf16.h>

// GateAttentionUnit. B=16, N=512, D=1024, E=2048, S=128, F=2E+S=4224.
// CONFIRMED: all 10 inputs fp32, output fp32. Internal compute bf16 MFMA.
//
// Pipeline:
//   P  prologue (fused): rope tables | uv_w->bf16 | o_w->bf16 | layernorm
//   K2 gemm<4,EpiUV>: silu(xn @ uv_wb^T + uv_b) -> u | vT | (base->rope->q,k
//        fused in the blockIdx.y==32 blocks' epilogue: base slice lives in
//        LDS, post() applies gamma/beta+rope, writes qb/kb)   [8192 x 4224]
//   K4 gemm<4,EpiQK>:   km = relu(q@k^T/512 + relpos)^2 (d_out)    [16][512][512]
//   K5 gemm<8,EpiAttn>: out2 = u * (km @ vT^T), out2 aliases u     [8192 x 2048]
//   K6 gemm<4,EpiOut>:  out = out2 @ o_wb^T + o_b + x  (fp32 out)  [8192 x 1024]
//
// R15 -> R16: K3 (rope_qk, 8192-block launch) ELIMINATED by fusing rope into
// K2's epilogue. Blocks with tileN==4096 compute the full 128-col base slice
// for their 128 rows -> stage bf16 base in the 32KB LDS (free after K-loop),
// __syncthreads, post(): gamma/beta + rope, write q/k directly. Same bf16
// values, same fp32 math, same tables => bit-exact vs K3. q/k MOVED to
// d_out [28MiB,32MiB) (old spot [0,4M) aliases xn, K2's live A operand).
// LDS base layout rotated by 2*row elements so post()'s reads are bank-
// conflict-free (unrotated col-read = 32-way conflict). GEMM core + mapping
// + prologue frozen (R13/R15-verified; R14 proved mapping swap costs 4x
// FETCH; 3 sync-structure rewrites failed -- do not re-edit).
//
// ws (68 MiB): u [0,32M) (out2 alias), vT [32M,64M), o_wb [64M,68M)
// d_out (33.55 MB fp32) dead-interval scratch:
//   xn [0,16M) P->K2 ; uv_wb [16M,24.65M) P->K2 ; tables [26.25M,26.5M)
//   P->K2 ; qb [28M,30M) kb [30M,32M) K2->K4 ; km [4M,12M) K4->K5 (xn dead).
//   All dead before K6 writes d_out.

typedef __bf16 bf16_t;
typedef __bf16 bf16x4 __attribute__((ext_vector_type(4)));
typedef __bf16 bf16x8 __attribute__((ext_vector_type(8)));
typedef float  f32x4  __attribute__((ext_vector_type(4)));

__device__ __forceinline__ void async16(const void* g, void* l) {
  __builtin_amdgcn_global_load_lds(
      (const __attribute__((address_space(1))) void*)g,
      (__attribute__((address_space(3))) void*)l, 16, 0, 0);
}

// ---------------- sentinel (ws guard diagnostics) ----------------
__global__ __launch_bounds__(256) void fill_const(float* __restrict__ out,
                                                  float val, int n) {
  int i = blockIdx.x * 256 + threadIdx.x;
  if (i < n) out[i] = val;
}

// ---------------- P: fused prologue ----------------
// blocks [0,128):        rope cos/sin tables (512x64, fp64 ref-exact path)
// blocks [128,4352):     cvt uv_w -> bf16   (1,081,344 f32x4)
// blocks [4352,6400):    cvt o_w -> bf16    (524,288 f32x4)
// blocks [6400,14592):   layernorm row = bid-6400
__global__ __launch_bounds__(256) void prologue(
    const float* __restrict__ x, const float* __restrict__ ln_w,
    const float* __restrict__ ln_b, bf16_t* __restrict__ xn,
    const float* __restrict__ uv_w, bf16_t* __restrict__ uv_wb,
    const float* __restrict__ o_w, bf16_t* __restrict__ o_wb,
    float* __restrict__ cosT, float* __restrict__ sinT) {
  const int bid = blockIdx.x;
  const int tid = threadIdx.x;
  if (bid < 128) {
    int idx = bid * 256 + tid;   // 512*64
    int n = idx >> 6, j = idx & 63;
    float invf = (float)pow(10000.0, (double)j * (1.0 / 64.0));
    float angf = (float)n * invf;
    cosT[idx] = (float)cos((double)angf);
    sinT[idx] = (float)sin((double)angf);
  } else if (bid < 6400) {
    const float* in = (bid < 4352) ? uv_w : o_w;
    bf16_t* out = (bid < 4352) ? uv_wb : o_wb;
    int i = (bid - ((bid < 4352) ? 128 : 4352)) * 256 + tid;
    f32x4 v = ((const f32x4*)in)[i];
    bf16x4 o;
    o[0] = (__bf16)v[0]; o[1] = (__bf16)v[1];
    o[2] = (__bf16)v[2]; o[3] = (__bf16)v[3];
    ((bf16x4*)out)[i] = o;
  } else {
    int row = bid - 6400;
    f32x4 v = *(const f32x4*)(x + (size_t)row * 1024 + tid * 4);
    float s = v[0] + v[1] + v[2] + v[3];
    float s2 = v[0]*v[0] + v[1]*v[1] + v[2]*v[2] + v[3]*v[3];
    for (int o = 32; o > 0; o >>= 1) {
      s += __shfl_down(s, o);
      s2 += __shfl_down(s2, o);
    }
    __shared__ float ps[4], ps2[4];
    if ((tid & 63) == 0) { ps[tid >> 6] = s; ps2[tid >> 6] = s2; }
    __syncthreads();
    float st = ps[0] + ps[1] + ps[2] + ps[3];
    float st2 = ps2[0] + ps2[1] + ps2[2] + ps2[3];
    float mean = st * (1.f / 1024.f);
    float var = st2 * (1.f / 1024.f) - mean * mean;
    float inv = 1.f / sqrtf(var + 1e-5f);
    bf16x4 o4;
    for (int i = 0; i < 4; i++) {
      float wn = ln_w[tid * 4 + i], bn = ln_b[tid * 4 + i];
      o4[i] = (__bf16)((v[i] - mean) * inv * wn + bn);
    }
    *(bf16x4*)(xn + (size_t)row * 1024 + tid * 4) = o4;
  }
}

// ------- epilogues: f32x4 = C rows m0..m0+3, col n. NaN-scrub clamps. ------
struct EpiUV {   // + uv_b, silu -> u | vT | base->LDS (rope fused via post)
  static constexpr bool HAS_POST = true;
  const float* uv_b;
  bf16_t* u;
  bf16_t* vT;      // [16][2048][512]
  const float* gamma;
  const float* beta;
  const float* cosT;
  const float* sinT;
  bf16_t* qb;
  bf16_t* kb;
  __device__ void operator()(int b, int m0, int n, f32x4 a4, bf16_t* sm,
                             int tileM, int tileN) const {
    float bn = uv_b[n];
    bf16_t s[4];
#pragma unroll
    for (int r = 0; r < 4; r++) {
      float xv = a4[r] + bn;
      // silu via v_rcp_f32 (R10): '/' expands to div_scale/fmas/fixup.
      float sv = xv * __builtin_amdgcn_rcpf(1.f + __expf(-xv));
      sv = fminf(fmaxf(sv, -100.f), 100.f);
      s[r] = (__bf16)sv;
    }
    if (n < 2048) {
#pragma unroll
      for (int r = 0; r < 4; r++) u[(size_t)(m0 + r) * 2048 + n] = s[r];
    } else if (n < 4096) {
      // transpose store: 4 consecutive nseq for fixed e -> one 8B store
      int bb = m0 >> 9, ns = m0 & 511;
      bf16x4 p; p[0] = s[0]; p[1] = s[1]; p[2] = s[2]; p[3] = s[3];
      *(bf16x4*)(vT + ((size_t)bb * 2048 + (n - 2048)) * 512 + ns) = p;
    } else {
      // base slice -> LDS, rotated by 2*row elements (bank-conflict-free
      // column reads in post; unrotated col-read = 32-way conflict).
#pragma unroll
      for (int r = 0; r < 4; r++) {
        int rl = m0 - tileM + r;
        sm[rl * 128 + ((n - 4096 + 2 * rl) & 127)] = s[r];
      }
    }
  }
  // post: 2 threads/row (halves of s-range); identical math to old rope_qk.
  __device__ void post(int tileM, int tid, const bf16_t* sm) const {
    int r = tid >> 1, half = tid & 1;
    int m = tileM + r;              // global row = b*512 + nseq
    int nseq = m & 511;
    const float* cT = cosT + nseq * 64;
    const float* sT = sinT + nseq * 64;
    const bf16_t* row = sm + r * 128;
    bf16_t* qd = qb + (size_t)m * 128 + half * 64;
    bf16_t* kd = kb + (size_t)m * 128 + half * 64;
#pragma unroll
    for (int v = 0; v < 8; v++) {
      bf16x8 qa, ka;
#pragma unroll
      for (int e = 0; e < 8; e++) {
        int jj = v * 8 + e;
        float b1 = (float)row[(jj + 2 * r) & 127];
        float b2 = (float)row[(jj + 64 + 2 * r) & 127];
        float c = cT[jj], sn = sT[jj];
        float tq1 = b1 * gamma[jj]       + beta[jj];
        float tq2 = b2 * gamma[64 + jj]  + beta[64 + jj];
        float tk1 = b1 * gamma[128 + jj] + beta[128 + jj];
        float tk2 = b2 * gamma[192 + jj] + beta[192 + jj];
        qa[e] = (__bf16)(half ? (tq2 * c + tq1 * sn) : (tq1 * c - tq2 * sn));
        ka[e] = (__bf16)(half ? (tk2 * c + tk1 * sn) : (tk1 * c - tk2 * sn));
      }
      *(bf16x8*)(qd + v * 8) = qa;
      *(bf16x8*)(kd + v * 8) = ka;
    }
  }
};
struct EpiQK {   // clamp(relu(acc/512 + w_rel[511+j-i]))^2 -> km
  static constexpr bool HAS_POST = false;
  const float* w_rel;
  bf16_t* km;
  __device__ void operator()(int b, int i0, int j, f32x4 a4, bf16_t*, int,
                             int) const {
#pragma unroll
    for (int r = 0; r < 4; r++) {
      float bias = w_rel[511 + j - (i0 + r)];
      float t = fmaxf(a4[r] * (1.f / 512.f) + bias, 0.f);
      t = fminf(t, 100.f);
      km[((size_t)b * 512 + i0 + r) * 512 + j] = (__bf16)(t * t);
    }
  }
};
struct EpiAttn { // clamp(acc * u) -> out2 (out2 aliases u element-exactly)
  static constexpr bool HAS_POST = false;
  const bf16_t* u;
  bf16_t* out2;
  __device__ void operator()(int b, int i0, int e, f32x4 a4, bf16_t*, int,
                             int) const {
#pragma unroll
    for (int r = 0; r < 4; r++) {
      size_t m = (size_t)b * 512 + i0 + r;
      float uu = (float)u[m * 2048 + e];
      float rr = a4[r] * uu;
      rr = fminf(fmaxf(rr, -1e6f), 1e6f);
      out2[m * 2048 + e] = (__bf16)rr;
    }
  }
};
struct EpiOut {  // clamp(acc + o_b + shortcut) -> fp32 out
  static constexpr bool HAS_POST = false;
  const float* o_b;
  const float* x;
  float* out;
  __device__ void operator()(int b, int m0, int d, f32x4 a4, bf16_t*, int,
                             int) const {
    float ob = o_b[d];
#pragma unroll
    for (int r = 0; r < 4; r++) {
      long idx = (long)(m0 + r) * 1024 + d;
      float rr = a4[r] + ob + x[idx];
      rr = fminf(fmaxf(rr, -1e5f), 1e5f);
      out[idx] = rr;
    }
  }
};

// -------- templated NT GEMM (BK=32 dbuf, stage-after-barrier pipeline) -----
// C[m][n] = sum_k A[m][k]*B[n][k]; A,B bf16 K-contiguous. Block tile
// (MFR*32) x 128, 256 threads (4 waves 2x2); wave computes (MFR*16) x 64.
// BK=32. LDS: 2 buffers x {A MROWS*64B | B 8KB}. MFR=4: 32KB total.
// Block mapping: x->tileM (fast), y->tileN -- consecutive blocks share the
// SMALL B panel (fits per-XCD L2); L3 absorbs streamed-A re-reads. (R14
// proved the swap costs 4x FETCH + 12% time. Do not swap again.)
// Layout per matrix: 128B lines = 2 rows x 32 bf16. Within line L, 16B slot
// s holds source chunk g = s^(L&7) (row 2L+(g>>2), k-chunk g&3). Fragment
// read: 2-way bank alias max (free; R6-class layout, measured 0 conflicts).
// Loop: __syncthreads (drains tile-t loads, issued ONE compute phase ago);
// stage(t+1 -> buf^1); compute(buf). One barrier per K-32. PROVEN R13 --
// sync structure frozen (counted-vmcnt/raw-barrier variants failed 3x).
// HAS_POST epis: barrier before epilogue (LDS reuse vs other waves' last-
// tile ds_reads) and before post (base slice fully written).
template <int MFR, typename Epi>
__global__ __launch_bounds__(256, 2)
void gemm_nt(const bf16_t* __restrict__ A, const bf16_t* __restrict__ Bm,
             int lda, int ldb, int K, long sAz, long sBz, Epi epi) {
  constexpr int MROWS = MFR * 32;
  constexpr int ABYTES = MROWS * 64;      // A region per buffer
  constexpr int BUFB = ABYTES + 8192;     // + B region (128 rows x 64B)
  constexpr int NA = MROWS / 64;          // A staging iters (1KB blocks /4 waves)
  __shared__ __align__(16) char smem[2 * BUFB];
  const int tid = threadIdx.x;
  const int lane = tid & 63;
  const int wid = tid >> 6;
  const int wm = wid & 1, wn = wid >> 1;
  const int quad = lane >> 4, col16 = lane & 15;
  const int bz = blockIdx.z;
  const int tileM = blockIdx.x * MROWS;   // x -> M (R13-proven)
  const int tileN = blockIdx.y * 128;     // y -> N
  const bf16_t* Ab = A + (size_t)bz * sAz;
  const bf16_t* Bb = Bm + (size_t)bz * sBz;
  const int NT = K >> 5;                  // K-tiles of 32

  // Staging geometry: chunk c = u*64 + lane (u = i*4+wid wave-uniform 1KB id);
  // line L = c>>3, slot s = c&7; source g = s^(L&7) -> g is u-independent:
  // g = (lane&7) ^ ((lane>>3)&7). Source row = u*16 + 2*(lane>>3) + (g>>2).
  const int g = (lane & 7) ^ ((lane >> 3) & 7);
  const int rowb = 2 * (lane >> 3) + (g >> 2);
  const int kcb = (g & 3) * 8;            // element offset within row
  unsigned oA[NA], oB[2];
#pragma unroll
  for (int i = 0; i < NA; i++) {
    int u = i * 4 + wid;
    oA[i] = (unsigned)((tileM + u * 16 + rowb) * lda + kcb);
  }
#pragma unroll
  for (int i = 0; i < 2; i++) {
    int u = i * 4 + wid;
    oB[i] = (unsigned)((tileN + u * 16 + rowb) * ldb + kcb);
  }

  // Fragment byte offsets (row ml/nl, k-chunk quad).
  int offA[MFR], offB[4];
#pragma unroll
  for (int mt = 0; mt < MFR; mt++) {
    int ml = wm * (MFR * 16) + mt * 16 + col16;
    int L = ml >> 1, gg = (ml & 1) * 4 + quad;
    offA[mt] = L * 128 + ((gg ^ (L & 7)) * 16);
  }
#pragma unroll
  for (int nt = 0; nt < 4; nt++) {
    int nl = wn * 64 + nt * 16 + col16;
    int L = nl >> 1, gg = (nl & 1) * 4 + quad;
    offB[nt] = L * 128 + ((gg ^ (L & 7)) * 16);
  }

  auto stage = [&](int kt, int p) {       // (NA+2) async16/thread
    char* base = (char*)smem + p * BUFB;
    const unsigned ko = (unsigned)kt * 32;
#pragma unroll
    for (int i = 0; i < NA; i++)
      async16(Ab + oA[i] + ko, base + (i * 4 + wid) * 1024);
#pragma unroll
    for (int i = 0; i < 2; i++)
      async16(Bb + oB[i] + ko, base + ABYTES + (i * 4 + wid) * 1024);
  };

  f32x4 acc[MFR][4] = {};

  stage(0, 0);
#pragma unroll 2
  for (int t = 0; t < NT; t++) {
    __syncthreads();                      // tile-t loads drained (1 phase old)
    if (t + 1 < NT) stage(t + 1, (t + 1) & 1);
    const char* sA = (const char*)smem + (t & 1) * BUFB;
    const char* sB = sA + ABYTES;
    bf16x8 af[MFR], bfr[4];
#pragma unroll
    for (int mt = 0; mt < MFR; mt++) af[mt] = *(const bf16x8*)(sA + offA[mt]);
#pragma unroll
    for (int nt = 0; nt < 4; nt++) bfr[nt] = *(const bf16x8*)(sB + offB[nt]);
#pragma unroll
    for (int mt = 0; mt < MFR; mt++)
#pragma unroll
      for (int nt = 0; nt < 4; nt++)
        acc[mt][nt] = __builtin_amdgcn_mfma_f32_16x16x32_bf16(
            af[mt], bfr[nt], acc[mt][nt], 0, 0, 0);
  }

  bf16_t* smb = (bf16_t*)smem;
  if constexpr (Epi::HAS_POST) {
    // LDS about to be reused by the epilogue of tileN==4096 blocks: wait for
    // all waves' last-tile ds_reads before overwriting.
    if (tileN == 4096) __syncthreads();
  }
#pragma unroll
  for (int mt = 0; mt < MFR; mt++) {
    int gm = tileM + wm * (MFR * 16) + mt * 16 + quad * 4;
#pragma unroll
    for (int nt = 0; nt < 4; nt++) {
      int gn = tileN + wn * 64 + nt * 16 + col16;
      epi(bz, gm, gn, acc[mt][nt], smb, tileM, tileN);
    }
  }
  if constexpr (Epi::HAS_POST) {
    if (tileN == 4096) {
      __syncthreads();                    // base slice fully in LDS
      epi.post(tileM, tid, smb);
    }
  }
}

extern "C" void kernel_launch(void* const* d_in, const int* in_sizes, int n_in,
                              void* d_out, int out_size, void* d_ws, size_t ws_size,
                              hipStream_t stream) {
  const float* x = (const float*)d_in[0];
  const float* ln_w = (const float*)d_in[1];
  const float* ln_b = (const float*)d_in[2];
  const float* uv_w = (const float*)d_in[3];
  const float* uv_b = (const float*)d_in[4];
  const float* gamma = (const float*)d_in[5];
  const float* beta = (const float*)d_in[6];
  const float* o_w = (const float*)d_in[7];
  const float* o_b = (const float*)d_in[8];
  const float* w_rel = (const float*)d_in[9];
  float* out = (float*)d_out;

  const int NOUT = 8388608;
  const size_t WS_NEEDED = 71303168;   // 68 MiB (>=69.4 MiB proven in R5)
  if (ws_size < WS_NEEDED) {
    float wsMiB = (float)(ws_size >> 20);
    fill_const<<<dim3(32768), dim3(256), 0, stream>>>(out, 1000.f + wsMiB, NOUT);
    return;
  }

  // ws: u [0,32M) (out2 alias), vT [32M,64M), o_wb [64M,68M)
  char* ws = (char*)d_ws;
  bf16_t* u = (bf16_t*)(ws + 0);
  bf16_t* out2 = u;
  bf16_t* vT = (bf16_t*)(ws + 33554432);
  bf16_t* o_wb = (bf16_t*)(ws + 67108864);
  // d_out dead-interval scratch (33.55 MB fp32 region):
  char* ob = (char*)d_out;
  bf16_t* xn = (bf16_t*)ob;                       // [0, 16,777,216)
  bf16_t* uv_wb = (bf16_t*)(ob + 16777216);       // [16,777,216, 25,427,968)
  float* cosT = (float*)(ob + 27525120);          // [27,525,120, 27,656,192)
  float* sinT = (float*)(ob + 27656192);          // [27,656,192, 27,787,264)
  bf16_t* qb = (bf16_t*)(ob + 29360128);          // [28M, 30M)  K2->K4
  bf16_t* kb = (bf16_t*)(ob + 31457280);          // [30M, 32M)  K2->K4
  bf16_t* km = (bf16_t*)(ob + 4194304);           // [4M, 12M)   K4->K5

  // P: fused prologue (rope tables | cvt uv | cvt o | layernorm)
  prologue<<<dim3(14592), dim3(256), 0, stream>>>(
      x, ln_w, ln_b, xn, uv_w, uv_wb, o_w, o_wb, cosT, sinT);
  // K2: silu(xn @ uv_wb^T + uv_b) -> u | vT | q,k (rope fused):
  // M=8192, N=4224, K=1024
  gemm_nt<4><<<dim3(64, 33, 1), dim3(256), 0, stream>>>(
      xn, uv_wb, 1024, 1024, 1024, 0L, 0L,
      EpiUV{uv_b, u, vT, gamma, beta, cosT, sinT, qb, kb});
  // K4: km = relu(q@k^T/512 + bias)^2: per batch M=N=512, K=128
  gemm_nt<4><<<dim3(4, 4, 16), dim3(256), 0, stream>>>(
      qb, kb, 128, 128, 128, (long)512 * 128, (long)512 * 128, EpiQK{w_rel, km});
  // K5: out2 = u * (km @ v): per batch M=512, N=2048, K=512
  gemm_nt<8><<<dim3(2, 16, 16), dim3(256), 0, stream>>>(
      km, vT, 512, 512, 512, (long)512 * 512, (long)2048 * 512, EpiAttn{u, out2});
  // K6: out = out2 @ o_wb^T + o_b + x: M=8192, N=1024, K=2048
  gemm_nt<4><<<dim3(64, 8, 1), dim3(256), 0, stream>>>(
      out2, o_wb, 2048, 2048, 2048, 0L, 0L, EpiOut{o_b, x, out});
}